// Round 5
// baseline (742.611 us; speedup 1.0000x reference)
//
#include <hip/hip_runtime.h>

#define TT 1024
#define DD 32
#define HH 64

typedef __fp16 h2 __attribute__((ext_vector_type(2)));

__device__ __forceinline__ float fsig(float x) {
    float e = __builtin_amdgcn_exp2f(-1.4426950408889634f * x);
    return __builtin_amdgcn_rcpf(1.0f + e);
}

template<int CTRL>
__device__ __forceinline__ float fdpp(float x) {
    int r = __builtin_amdgcn_mov_dpp(__builtin_bit_cast(int, x), CTRL, 0xf, 0xf, true);
    return __builtin_bit_cast(float, r);
}

// lane^4 swizzle (BitMode: xor=4, and=0x1F) — DS pipe, off the VALU
__device__ __forceinline__ float fswz4(float x) {
    int r = __builtin_amdgcn_ds_swizzle(__builtin_bit_cast(int, x), 0x101F);
    return __builtin_bit_cast(float, r);
}

struct __attribute__((aligned(16))) H8 { h2 p[4]; };  // 8 f16 = 16 B

__device__ __forceinline__ void cvt4(float4 f, h2* d) {
    d[0] = __builtin_amdgcn_cvt_pkrtz(f.x, f.y);
    d[1] = __builtin_amdgcn_cvt_pkrtz(f.z, f.w);
}

// 1024 threads: tid<512 -> layer1, tid>=512 -> layer2 (one step behind).
// gtid = j*8 + c ; c = dot-dim chunk (0..7), gate for activation = c&3, j = output idx.
// Quad transpose-reduce (DPP) + xor-4 swizzle combine -> lane c holds gate (c&3) full sum.
__global__ __launch_bounds__(1024) __attribute__((amdgpu_waves_per_eu(4, 4)))
void lstm2_w16(
    const float* __restrict__ x,
    const float* __restrict__ w_ih_l0, const float* __restrict__ w_hh_l0,
    const float* __restrict__ b_ih_l0, const float* __restrict__ b_hh_l0,
    const float* __restrict__ w_ih_l1, const float* __restrict__ w_hh_l1,
    const float* __restrict__ b_ih_l1, const float* __restrict__ b_hh_l1,
    const float* __restrict__ w_fc,   const float* __restrict__ b_fc,
    float* __restrict__ out)
{
    const int b    = blockIdx.x;
    const int tid  = threadIdx.x;
    const bool isL1 = tid < 512;
    const int gtid = tid & 511;
    const int c_ch = gtid & 7;
    const int j    = gtid >> 3;
    const int ga   = (c_ch & 3) * 64 + j;   // gate row for activation

    __shared__ __attribute__((aligned(32))) __fp16 h1s[2][HH];
    __shared__ __attribute__((aligned(32))) __fp16 h2sB[2][HH];
    if (tid < HH) {
        h1s[0][tid] = (__fp16)0.f; h1s[1][tid] = (__fp16)0.f;
        h2sB[0][tid] = (__fp16)0.f; h2sB[1][tid] = (__fp16)0.f;
    }

    // per-lane activation constants: gate 2 -> tanh(x)=2*sigma(2x)-1, else sigma(x)
    const float kk = ((c_ch & 3) == 2) ? -2.885390081777927f : -1.4426950408889634f;
    const float aa = ((c_ch & 3) == 2) ? 2.0f : 1.0f;
    const float bb = ((c_ch & 3) == 2) ? -1.0f : 0.0f;

    // packed-f16 weights, register-resident.
    // L1 per gate m (stride 6):  [0..1]=w_ih 4 floats, [2..5]=w_hh 8 floats
    // L2 per gate m (stride 8):  [0..3]=w_ih(h1) 8 floats, [4..7]=w_hh(h2) 8 floats
    h2 wh[32];
    float bias;
    if (isL1) {
        #pragma unroll
        for (int m = 0; m < 4; ++m) {
            float4 fih = *(const float4*)(w_ih_l0 + (m*64 + j)*DD + c_ch*4);
            cvt4(fih, &wh[m*6 + 0]);
            const float4* phh = (const float4*)(w_hh_l0 + (m*64 + j)*HH + c_ch*8);
            cvt4(phh[0], &wh[m*6 + 2]);
            cvt4(phh[1], &wh[m*6 + 4]);
        }
        bias = b_ih_l0[ga] + b_hh_l0[ga];
    } else {
        #pragma unroll
        for (int m = 0; m < 4; ++m) {
            const float4* pih = (const float4*)(w_ih_l1 + (m*64 + j)*HH + c_ch*8);
            cvt4(pih[0], &wh[m*8 + 0]);
            cvt4(pih[1], &wh[m*8 + 2]);
            const float4* phh = (const float4*)(w_hh_l1 + (m*64 + j)*HH + c_ch*8);
            cvt4(phh[0], &wh[m*8 + 4]);
            cvt4(phh[1], &wh[m*8 + 6]);
        }
        bias = b_ih_l1[ga] + b_hh_l1[ga];
    }

    float cst = 0.0f;   // cell state (replicated across the 8 c-lanes of each j)

    // L1 x: this lane's 4-float chunk of the current row
    const float* xbase = x + (size_t)b * TT * DD + c_ch * 4;
    h2 xh[2];
    if (isL1) {
        float4 a0 = *(const float4*)xbase;
        xh[0] = __builtin_amdgcn_cvt_pkrtz(a0.x, a0.y);
        xh[1] = __builtin_amdgcn_cvt_pkrtz(a0.z, a0.w);
    }

    __syncthreads();

    for (int t = 0; t <= TT; ++t) {
        const int prev = (t + 1) & 1;
        const int cur  = t & 1;
        if (isL1) {
            if (t < TT) {
                const int tn = (t + 1 < TT) ? (t + 1) : t;
                float4 n0 = *(const float4*)(xbase + (size_t)tn * DD);

                H8 hq = *(const H8*)&h1s[prev][c_ch*8];

                float P[4];
                #pragma unroll
                for (int m = 0; m < 4; ++m) {
                    float s = 0.0f;
                    s = __builtin_amdgcn_fdot2(wh[m*6 + 0], xh[0], s, false);
                    s = __builtin_amdgcn_fdot2(wh[m*6 + 1], xh[1], s, false);
                    #pragma unroll
                    for (int k = 0; k < 4; ++k)
                        s = __builtin_amdgcn_fdot2(wh[m*6 + 2 + k], hq.p[k], s, false);
                    P[m] = s;
                }

                float t0 = P[0] + fdpp<0xB1>(P[0]);
                float t1 = P[1] + fdpp<0xB1>(P[1]);
                float t2 = P[2] + fdpp<0xB1>(P[2]);
                float t3 = P[3] + fdpp<0xB1>(P[3]);
                float Alo = (c_ch & 1) ? t1 : t0;
                float Ahi = (c_ch & 1) ? t3 : t2;
                float ulo = Alo + fdpp<0x4E>(Alo);
                float uhi = Ahi + fdpp<0x4E>(Ahi);
                float Sh = (c_ch & 2) ? uhi : ulo;
                float S = Sh + fswz4(Sh) + bias;

                float e = __builtin_amdgcn_exp2f(kk * S);
                float v = aa * __builtin_amdgcn_rcpf(1.0f + e) + bb;

                float gi = fdpp<0x00>(v);
                float gf = fdpp<0x55>(v);
                float gg = fdpp<0xAA>(v);
                float go = fdpp<0xFF>(v);
                cst = gf * cst + gi * gg;
                float e2 = __builtin_amdgcn_exp2f(-2.885390081777927f * cst);
                float th = 2.0f * __builtin_amdgcn_rcpf(1.0f + e2) - 1.0f;
                float hv = go * th;
                if (c_ch == 0) h1s[cur][j] = (__fp16)hv;

                xh[0] = __builtin_amdgcn_cvt_pkrtz(n0.x, n0.y);
                xh[1] = __builtin_amdgcn_cvt_pkrtz(n0.z, n0.w);
            }
        } else {
            if (t > 0) {
                H8 a1 = *(const H8*)&h1s[prev][c_ch*8];
                H8 a2 = *(const H8*)&h2sB[prev][c_ch*8];

                float P[4];
                #pragma unroll
                for (int m = 0; m < 4; ++m) {
                    float s = 0.0f;
                    #pragma unroll
                    for (int k = 0; k < 4; ++k)
                        s = __builtin_amdgcn_fdot2(wh[m*8 + k], a1.p[k], s, false);
                    #pragma unroll
                    for (int k = 0; k < 4; ++k)
                        s = __builtin_amdgcn_fdot2(wh[m*8 + 4 + k], a2.p[k], s, false);
                    P[m] = s;
                }

                float t0 = P[0] + fdpp<0xB1>(P[0]);
                float t1 = P[1] + fdpp<0xB1>(P[1]);
                float t2 = P[2] + fdpp<0xB1>(P[2]);
                float t3 = P[3] + fdpp<0xB1>(P[3]);
                float Alo = (c_ch & 1) ? t1 : t0;
                float Ahi = (c_ch & 1) ? t3 : t2;
                float ulo = Alo + fdpp<0x4E>(Alo);
                float uhi = Ahi + fdpp<0x4E>(Ahi);
                float Sh = (c_ch & 2) ? uhi : ulo;
                float S = Sh + fswz4(Sh) + bias;

                float e = __builtin_amdgcn_exp2f(kk * S);
                float v = aa * __builtin_amdgcn_rcpf(1.0f + e) + bb;

                float gi = fdpp<0x00>(v);
                float gf = fdpp<0x55>(v);
                float gg = fdpp<0xAA>(v);
                float go = fdpp<0xFF>(v);
                cst = gf * cst + gi * gg;
                float e2 = __builtin_amdgcn_exp2f(-2.885390081777927f * cst);
                float th = 2.0f * __builtin_amdgcn_rcpf(1.0f + e2) - 1.0f;
                float hv = go * th;
                if (c_ch == 0) h2sB[cur][j] = (__fp16)hv;
            }
        }
        __syncthreads();
    }

    // h2(T-1) is in h2sB[0] (written at iter t=1024, cur=0). FC + sigmoid.
    if (tid < HH) {
        float v = (float)h2sB[0][tid] * w_fc[tid];
        #pragma unroll
        for (int off = 32; off > 0; off >>= 1) v += __shfl_down(v, off);
        if (tid == 0) out[b] = fsig(v + b_fc[0]);
    }
}

extern "C" void kernel_launch(void* const* d_in, const int* in_sizes, int n_in,
                              void* d_out, int out_size, void* d_ws, size_t ws_size,
                              hipStream_t stream) {
    lstm2_w16<<<dim3(256), dim3(1024), 0, stream>>>(
        (const float*)d_in[0],
        (const float*)d_in[1], (const float*)d_in[2],
        (const float*)d_in[3], (const float*)d_in[4],
        (const float*)d_in[5], (const float*)d_in[6],
        (const float*)d_in[7], (const float*)d_in[8],
        (const float*)d_in[9], (const float*)d_in[10],
        (float*)d_out);
}

// Round 6
// 565.642 us; speedup vs baseline: 1.3129x; 1.3129x over previous
//
#include <hip/hip_runtime.h>

#define TT 1024
#define DD 32
#define HH 64

typedef __fp16 h2 __attribute__((ext_vector_type(2)));

__device__ __forceinline__ float fsig(float x) {
    float e = __builtin_amdgcn_exp2f(-1.4426950408889634f * x);
    return __builtin_amdgcn_rcpf(1.0f + e);
}

// quad_perm DPP move (VALU pipe, no LDS)
template<int CTRL>
__device__ __forceinline__ float fdpp(float x) {
    int r = __builtin_amdgcn_mov_dpp(__builtin_bit_cast(int, x), CTRL, 0xf, 0xf, true);
    return __builtin_bit_cast(float, r);
}

struct __attribute__((aligned(16))) H16 { h2 p[8]; };  // 16 f16 = 32 B

__device__ __forceinline__ void cvt4rtn(float4 f, h2* d) {
    d[0] = __builtin_amdgcn_cvt_pkrtz(f.x, f.y);
    d[1] = __builtin_amdgcn_cvt_pkrtz(f.z, f.w);
}

// Thread org (R4): tid<256 -> layer1, tid>=256 -> layer2 (1 step behind).
// gtid = j*4+q ; q = dot-dim chunk AND gate type; j = output idx.
__global__ __launch_bounds__(512) __attribute__((amdgpu_waves_per_eu(1, 2)))
void lstm2_vpin(
    const float* __restrict__ x,
    const float* __restrict__ w_ih_l0, const float* __restrict__ w_hh_l0,
    const float* __restrict__ b_ih_l0, const float* __restrict__ b_hh_l0,
    const float* __restrict__ w_ih_l1, const float* __restrict__ w_hh_l1,
    const float* __restrict__ b_ih_l1, const float* __restrict__ b_hh_l1,
    const float* __restrict__ w_fc,   const float* __restrict__ b_fc,
    float* __restrict__ out)
{
    const int b    = blockIdx.x;
    const int tid  = threadIdx.x;
    const bool isL1 = tid < 256;
    const int gtid = tid & 255;
    const int q    = gtid & 3;
    const int j    = gtid >> 2;
    const int g    = q * 64 + j;

    __shared__ __attribute__((aligned(32))) __fp16 h1s[2][HH];
    __shared__ __attribute__((aligned(32))) __fp16 h2sB[2][HH];
    if (tid < HH) {
        h1s[0][tid] = (__fp16)0.f; h1s[1][tid] = (__fp16)0.f;
        h2sB[0][tid] = (__fp16)0.f; h2sB[1][tid] = (__fp16)0.f;
    }

    // per-lane activation constants: q==2 -> tanh(x)=2*sigma(2x)-1, else sigma(x)
    const float kk = (q == 2) ? -2.885390081777927f : -1.4426950408889634f;
    const float aa = (q == 2) ? 2.0f : 1.0f;
    const float bb = (q == 2) ? -1.0f : 0.0f;

    // packed-f16 weights, register-resident.
    // L1: per gate m, stride 12: [0..3]=w_ih chunk (8), [4..11]=w_hh chunk (16)
    // L2: per gate m, stride 16: [0..7]=w_ih chunk (16), [8..15]=w_hh chunk (16)
    h2 wh[64];
    float bias;
    if (isL1) {
        #pragma unroll
        for (int m = 0; m < 4; ++m) {
            const float4* pih = (const float4*)(w_ih_l0 + (m*64 + j)*DD + q*8);
            cvt4rtn(pih[0], &wh[m*12 + 0]);
            cvt4rtn(pih[1], &wh[m*12 + 2]);
            const float4* phh = (const float4*)(w_hh_l0 + (m*64 + j)*HH + q*16);
            cvt4rtn(phh[0], &wh[m*12 + 4]);
            cvt4rtn(phh[1], &wh[m*12 + 6]);
            cvt4rtn(phh[2], &wh[m*12 + 8]);
            cvt4rtn(phh[3], &wh[m*12 + 10]);
        }
        bias = b_ih_l0[g] + b_hh_l0[g];
    } else {
        #pragma unroll
        for (int m = 0; m < 4; ++m) {
            const float4* pih = (const float4*)(w_ih_l1 + (m*64 + j)*HH + q*16);
            cvt4rtn(pih[0], &wh[m*16 + 0]);
            cvt4rtn(pih[1], &wh[m*16 + 2]);
            cvt4rtn(pih[2], &wh[m*16 + 4]);
            cvt4rtn(pih[3], &wh[m*16 + 6]);
            const float4* phh = (const float4*)(w_hh_l1 + (m*64 + j)*HH + q*16);
            cvt4rtn(phh[0], &wh[m*16 + 8]);
            cvt4rtn(phh[1], &wh[m*16 + 10]);
            cvt4rtn(phh[2], &wh[m*16 + 12]);
            cvt4rtn(phh[3], &wh[m*16 + 14]);
        }
        bias = b_ih_l1[g] + b_hh_l1[g];
    }

    // Pin all 64 weight dwords into arch VGPRs (no-op asm; forces "v" class so
    // the allocator cannot park them in AGPRs and pay v_accvgpr_read per use).
    asm volatile("" : "+v"(wh[0]), "+v"(wh[1]), "+v"(wh[2]), "+v"(wh[3]),
                      "+v"(wh[4]), "+v"(wh[5]), "+v"(wh[6]), "+v"(wh[7]),
                      "+v"(wh[8]), "+v"(wh[9]), "+v"(wh[10]), "+v"(wh[11]),
                      "+v"(wh[12]), "+v"(wh[13]), "+v"(wh[14]), "+v"(wh[15]));
    asm volatile("" : "+v"(wh[16]), "+v"(wh[17]), "+v"(wh[18]), "+v"(wh[19]),
                      "+v"(wh[20]), "+v"(wh[21]), "+v"(wh[22]), "+v"(wh[23]),
                      "+v"(wh[24]), "+v"(wh[25]), "+v"(wh[26]), "+v"(wh[27]),
                      "+v"(wh[28]), "+v"(wh[29]), "+v"(wh[30]), "+v"(wh[31]));
    asm volatile("" : "+v"(wh[32]), "+v"(wh[33]), "+v"(wh[34]), "+v"(wh[35]),
                      "+v"(wh[36]), "+v"(wh[37]), "+v"(wh[38]), "+v"(wh[39]),
                      "+v"(wh[40]), "+v"(wh[41]), "+v"(wh[42]), "+v"(wh[43]),
                      "+v"(wh[44]), "+v"(wh[45]), "+v"(wh[46]), "+v"(wh[47]));
    asm volatile("" : "+v"(wh[48]), "+v"(wh[49]), "+v"(wh[50]), "+v"(wh[51]),
                      "+v"(wh[52]), "+v"(wh[53]), "+v"(wh[54]), "+v"(wh[55]),
                      "+v"(wh[56]), "+v"(wh[57]), "+v"(wh[58]), "+v"(wh[59]),
                      "+v"(wh[60]), "+v"(wh[61]), "+v"(wh[62]), "+v"(wh[63]));

    float c = 0.0f;

    // L1 x prefetch: this lane's 8-float chunk of the current row, packed f16
    const float* xbase = x + (size_t)b * TT * DD + q * 8;
    h2 xh[4];
    if (isL1) {
        const float4* xp = (const float4*)xbase;
        float4 a0 = xp[0], a1 = xp[1];
        xh[0] = __builtin_amdgcn_cvt_pkrtz(a0.x, a0.y);
        xh[1] = __builtin_amdgcn_cvt_pkrtz(a0.z, a0.w);
        xh[2] = __builtin_amdgcn_cvt_pkrtz(a1.x, a1.y);
        xh[3] = __builtin_amdgcn_cvt_pkrtz(a1.z, a1.w);
    }

    __syncthreads();

    for (int t = 0; t <= TT; ++t) {
        const int prev = (t + 1) & 1;
        const int cur  = t & 1;
        if (isL1) {
            if (t < TT) {
                const int tn = (t + 1 < TT) ? (t + 1) : t;
                const float4* xp = (const float4*)(xbase + (size_t)tn * DD);
                float4 n0 = xp[0], n1 = xp[1];

                H16 hq = *(const H16*)&h1s[prev][q*16];

                float P[4];
                #pragma unroll
                for (int m = 0; m < 4; ++m) {
                    float s = 0.0f;
                    #pragma unroll
                    for (int k = 0; k < 4; ++k)
                        s = __builtin_amdgcn_fdot2(wh[m*12 + k], xh[k], s, false);
                    #pragma unroll
                    for (int k = 0; k < 8; ++k)
                        s = __builtin_amdgcn_fdot2(wh[m*12 + 4 + k], hq.p[k], s, false);
                    P[m] = s;
                }

                float t0 = P[0] + fdpp<0xB1>(P[0]);
                float t1 = P[1] + fdpp<0xB1>(P[1]);
                float t2 = P[2] + fdpp<0xB1>(P[2]);
                float t3 = P[3] + fdpp<0xB1>(P[3]);
                float Alo = (q & 1) ? t1 : t0;
                float Ahi = (q & 1) ? t3 : t2;
                float ulo = Alo + fdpp<0x4E>(Alo);
                float uhi = Ahi + fdpp<0x4E>(Ahi);
                float S = ((q & 2) ? uhi : ulo) + bias;

                float e = __builtin_amdgcn_exp2f(kk * S);
                float v = aa * __builtin_amdgcn_rcpf(1.0f + e) + bb;

                float gi = fdpp<0x00>(v);
                float gf = fdpp<0x55>(v);
                float gg = fdpp<0xAA>(v);
                float go = fdpp<0xFF>(v);
                c = gf * c + gi * gg;
                float e2 = __builtin_amdgcn_exp2f(-2.885390081777927f * c);
                float th = 2.0f * __builtin_amdgcn_rcpf(1.0f + e2) - 1.0f;
                float hv = go * th;
                if (q == 0) h1s[cur][j] = (__fp16)hv;

                xh[0] = __builtin_amdgcn_cvt_pkrtz(n0.x, n0.y);
                xh[1] = __builtin_amdgcn_cvt_pkrtz(n0.z, n0.w);
                xh[2] = __builtin_amdgcn_cvt_pkrtz(n1.x, n1.y);
                xh[3] = __builtin_amdgcn_cvt_pkrtz(n1.z, n1.w);
            }
        } else {
            if (t > 0) {
                H16 a1 = *(const H16*)&h1s[prev][q*16];
                H16 a2 = *(const H16*)&h2sB[prev][q*16];

                float P[4];
                #pragma unroll
                for (int m = 0; m < 4; ++m) {
                    float s = 0.0f;
                    #pragma unroll
                    for (int k = 0; k < 8; ++k)
                        s = __builtin_amdgcn_fdot2(wh[m*16 + k], a1.p[k], s, false);
                    #pragma unroll
                    for (int k = 0; k < 8; ++k)
                        s = __builtin_amdgcn_fdot2(wh[m*16 + 8 + k], a2.p[k], s, false);
                    P[m] = s;
                }

                float t0 = P[0] + fdpp<0xB1>(P[0]);
                float t1 = P[1] + fdpp<0xB1>(P[1]);
                float t2 = P[2] + fdpp<0xB1>(P[2]);
                float t3 = P[3] + fdpp<0xB1>(P[3]);
                float Alo = (q & 1) ? t1 : t0;
                float Ahi = (q & 1) ? t3 : t2;
                float ulo = Alo + fdpp<0x4E>(Alo);
                float uhi = Ahi + fdpp<0x4E>(Alo);
                // NOTE: line above must use Ahi — keep correct version:
                uhi = Ahi + fdpp<0x4E>(Ahi);
                float S = ((q & 2) ? uhi : ulo) + bias;

                float e = __builtin_amdgcn_exp2f(kk * S);
                float v = aa * __builtin_amdgcn_rcpf(1.0f + e) + bb;

                float gi = fdpp<0x00>(v);
                float gf = fdpp<0x55>(v);
                float gg = fdpp<0xAA>(v);
                float go = fdpp<0xFF>(v);
                c = gf * c + gi * gg;
                float e2 = __builtin_amdgcn_exp2f(-2.885390081777927f * c);
                float th = 2.0f * __builtin_amdgcn_rcpf(1.0f + e2) - 1.0f;
                float hv = go * th;
                if (q == 0) h2sB[cur][j] = (__fp16)hv;
            }
        }
        __syncthreads();
    }

    // h2(T-1) is in h2sB[0] (written at iter t=1024, cur=0). FC + sigmoid.
    if (tid < HH) {
        float v = (float)h2sB[0][tid] * w_fc[tid];
        #pragma unroll
        for (int off = 32; off > 0; off >>= 1) v += __shfl_down(v, off);
        if (tid == 0) out[b] = fsig(v + b_fc[0]);
    }
}

extern "C" void kernel_launch(void* const* d_in, const int* in_sizes, int n_in,
                              void* d_out, int out_size, void* d_ws, size_t ws_size,
                              hipStream_t stream) {
    lstm2_vpin<<<dim3(256), dim3(512), 0, stream>>>(
        (const float*)d_in[0],
        (const float*)d_in[1], (const float*)d_in[2],
        (const float*)d_in[3], (const float*)d_in[4],
        (const float*)d_in[5], (const float*)d_in[6],
        (const float*)d_in[7], (const float*)d_in[8],
        (const float*)d_in[9], (const float*)d_in[10],
        (float*)d_out);
}